// Round 1
// baseline (262.833 us; speedup 1.0000x reference)
//
#include <hip/hip_runtime.h>
#include <math.h>

#define B_ 4
#define N_ 4096
#define C_ 32
#define S_ 4096

// Extended-precision argument reduction: given fp32 phase p (|p| up to ~2.6e4 rad),
// compute r = p/(2*pi) mod 1 in [-0.5, 0.5] accurately (~1e-7 rev), then use the
// HW sin/cos which take REVOLUTIONS. This matches reference sin/cos(fp32 phase)
// far better than raw fast-math range reduction at large |p|.
__device__ __forceinline__ void sincos_ref(float p, float& sn, float& cs) {
    const double INV2PI_D = 0.15915494309189535;
    const float HI = (float)INV2PI_D;
    const float LO = (float)(INV2PI_D - (double)HI);
    float hi = p * HI;
    float e  = fmaf(p, HI, -hi);   // exact residual of the product
    e = fmaf(p, LO, e);
    float k = rintf(hi);
    float r = (hi - k) + e;        // revolutions, in [-0.5, 0.5]
#if __has_builtin(__builtin_amdgcn_sinf)
    sn = __builtin_amdgcn_sinf(r); // sin(2*pi*r)
    cs = __builtin_amdgcn_cosf(r);
#else
    float a = r * 6.2831853071795864769f;
    sn = __sinf(a);
    cs = __cosf(a);
#endif
}

// One thread per output row s; 64 fp32 accumulators (32 re + 32 im).
// Grid: (S/256, K, B). Each block handles one chunk of N (chunk = N/K).
// DIRECT=1: K==1, write |z| straight to out. DIRECT=0: write partials to ws.
template<int DIRECT>
__global__ __launch_bounds__(256)
void fudft_partial(const float* __restrict__ x,      // [B][N][C]
                   const float* __restrict__ t,      // [B][N]
                   const float* __restrict__ freqs,  // [S]
                   float* __restrict__ part,         // [B][K][S][2*C]
                   float* __restrict__ out,          // [B][S][C]
                   int K, int chunk)
{
    const int s = blockIdx.x * 256 + threadIdx.x;
    const int k = blockIdx.y;
    const int b = blockIdx.z;

    // Mirror reference fp32 op order: rows = fp32(-2pi/n) * fp32(freqs*(n-1))
    const float NEG2PI_N = (float)(-2.0 * M_PI / (double)N_);
    const float row = (freqs[s] * (float)(N_ - 1)) * NEG2PI_N;

    const float* __restrict__ xb = x + ((size_t)b * N_ + (size_t)k * chunk) * C_;
    const float* __restrict__ tb = t + (size_t)b * N_ + (size_t)k * chunk;

    float accR[C_], accI[C_];
#pragma unroll
    for (int c = 0; c < C_; ++c) { accR[c] = 0.f; accI[c] = 0.f; }

#pragma unroll 2
    for (int j = 0; j < chunk; ++j) {
        const float col = tb[j] * (float)(N_ - 1);   // cols = t*(n-1), fp32
        const float p = row * col;                   // fp32 product (as reference)
        float sn, cs;
        sincos_ref(p, sn, cs);

        // x row is wave-uniform -> expect s_load_dwordx4; FMA takes SGPR operand.
        const float4* __restrict__ xr4 =
            reinterpret_cast<const float4*>(xb + (size_t)j * C_);
        float xv[C_];
#pragma unroll
        for (int q = 0; q < C_ / 4; ++q) {
            const float4 v = xr4[q];
            xv[4 * q + 0] = v.x; xv[4 * q + 1] = v.y;
            xv[4 * q + 2] = v.z; xv[4 * q + 3] = v.w;
        }
#pragma unroll
        for (int c = 0; c < C_; ++c) {
            accR[c] = fmaf(cs, xv[c], accR[c]);
            accI[c] = fmaf(sn, xv[c], accI[c]);
        }
    }

    if (DIRECT) {
        float* __restrict__ dst = out + ((size_t)b * S_ + (size_t)s) * C_;
        const bool zero = (s == 0) || (s == S_ - 1);
#pragma unroll
        for (int c = 0; c < C_; ++c) {
            float m = sqrtf(fmaf(accR[c], accR[c], accI[c] * accI[c])) * 0.015625f;
            dst[c] = zero ? 0.f : m;
        }
    } else {
        float* __restrict__ dst =
            part + (((size_t)b * K + (size_t)k) * S_ + (size_t)s) * (2 * C_);
#pragma unroll
        for (int c = 0; c < C_; c += 2) {
            float4 v = make_float4(accR[c], accI[c], accR[c + 1], accI[c + 1]);
            *reinterpret_cast<float4*>(dst + 2 * c) = v;
        }
    }
}

// Reduce K partials, magnitude, zero first/last rows. One thread per (b,s,c).
__global__ __launch_bounds__(256)
void fudft_reduce(const float* __restrict__ part, float* __restrict__ out, int K)
{
    const int idx = blockIdx.x * 256 + threadIdx.x;
    if (idx >= B_ * S_ * C_) return;
    const int c = idx & (C_ - 1);
    const int s = (idx >> 5) & (S_ - 1);
    const int b = idx >> 17;

    float re = 0.f, im = 0.f;
    for (int k = 0; k < K; ++k) {
        const float2 v = *reinterpret_cast<const float2*>(
            part + (((size_t)b * K + (size_t)k) * S_ + (size_t)s) * (2 * C_) + 2 * c);
        re += v.x; im += v.y;
    }
    float m = sqrtf(fmaf(re, re, im * im)) * 0.015625f;  // * 1/sqrt(4096)
    if (s == 0 || s == S_ - 1) m = 0.f;
    out[idx] = m;
}

extern "C" void kernel_launch(void* const* d_in, const int* in_sizes, int n_in,
                              void* d_out, int out_size, void* d_ws, size_t ws_size,
                              hipStream_t stream) {
    const float* x = (const float*)d_in[0];
    const float* t = (const float*)d_in[1];
    const float* f = (const float*)d_in[2];
    float* out = (float*)d_out;

    const size_t bytes_per_k = (size_t)B_ * S_ * 2 * C_ * sizeof(float);  // 4.19 MB
    int K = (int)(ws_size / bytes_per_k);
    if (K >= 8) K = 8; else if (K >= 4) K = 4; else if (K >= 2) K = 2;
    else if (K >= 1) K = 1; else K = 0;

    if (K >= 1) {
        const int chunk = N_ / K;
        dim3 grid(S_ / 256, K, B_);
        fudft_partial<0><<<grid, 256, 0, stream>>>(x, t, f, (float*)d_ws, out, K, chunk);
        const int total = B_ * S_ * C_;
        fudft_reduce<<<(total + 255) / 256, 256, 0, stream>>>((const float*)d_ws, out, K);
    } else {
        // ws too small for even one partial set: fused direct path (fewer blocks, still correct)
        dim3 grid(S_ / 256, 1, B_);
        fudft_partial<1><<<grid, 256, 0, stream>>>(x, t, f, nullptr, out, 1, N_);
    }
}

// Round 2
// 211.247 us; speedup vs baseline: 1.2442x; 1.2442x over previous
//
#include <hip/hip_runtime.h>
#include <math.h>

#define B_ 4
#define N_ 4096
#define C_ 32
#define S_ 4096
#define PJ 64   // x rows per LDS panel

#define AS1(p) ((const __attribute__((address_space(1))) void*)(p))
#define AS3(p) ((__attribute__((address_space(3))) void*)(p))

// Extended-precision reduction: r = p/(2pi) mod 1 in [-0.5,0.5], then HW
// sin/cos (revolutions input). Matches reference sin/cos(fp32 phase) to ~1e-6.
__device__ __forceinline__ void sincos_ref(float p, float& sn, float& cs) {
    const double INV2PI_D = 0.15915494309189535;
    const float HI = (float)INV2PI_D;
    const float LO = (float)(INV2PI_D - (double)HI);
    float hi = p * HI;
    float e  = fmaf(p, HI, -hi);
    e = fmaf(p, LO, e);
    float k = rintf(hi);
    float r = (hi - k) + e;
    sn = __builtin_amdgcn_sinf(r);
    cs = __builtin_amdgcn_cosf(r);
}

// One thread per output row s; 64 fp32 accumulators.
// x/t panels staged into LDS via global_load_lds (double-buffered) so the
// inner loop reads via ds_read_b128 (in-order lgkmcnt -> pipelines), not SMEM.
template<int DIRECT>
__global__ __launch_bounds__(256)
void fudft_partial(const float* __restrict__ x,      // [B][N][C]
                   const float* __restrict__ t,      // [B][N]
                   const float* __restrict__ freqs,  // [S]
                   float* __restrict__ part,         // [B][K][S][2*C]
                   float* __restrict__ out,          // [B][S][C]
                   int K, int chunk)
{
    __shared__ float xs[2][PJ * C_];   // 2 x 8 KB
    __shared__ float ts[2][PJ];        // 2 x 256 B

    const int tid  = threadIdx.x;
    const int wid  = tid >> 6;
    const int lane = tid & 63;
    const int s = blockIdx.x * 256 + tid;
    const int k = blockIdx.y;
    const int b = blockIdx.z;

    const float NEG2PI_N = (float)(-2.0 * M_PI / (double)N_);
    const float row = (freqs[s] * (float)(N_ - 1)) * NEG2PI_N;

    const float* __restrict__ xb = x + ((size_t)b * N_ + (size_t)k * chunk) * C_;
    const float* __restrict__ tb = t + (size_t)b * N_ + (size_t)k * chunk;

    float accR[C_], accI[C_];
#pragma unroll
    for (int c = 0; c < C_; ++c) { accR[c] = 0.f; accI[c] = 0.f; }

    const int npan = chunk / PJ;

    // ---- staging: one panel = PJ rows of x (8 KB) + PJ t values (256 B) ----
    auto stage = [&](int buf, int pan) {
        const float* gx = xb + (size_t)pan * PJ * C_;   // contiguous 8 KB
        // 2 block-wide 16B global_load_lds ops cover 8 KB (256 lanes x 16 B x 2)
#pragma unroll
        for (int i = 0; i < 2; ++i) {
            const float* g = gx + (size_t)(i * 256 + tid) * 4;          // per-lane src
            float* l = &xs[buf][(size_t)(i * 256 + wid * 64) * 4];      // wave-uniform dst base
            __builtin_amdgcn_global_load_lds(AS1(g), AS3(l), 16, 0, 0);
        }
        if (wid == 0) {
            const float* g = tb + pan * PJ + lane;                      // per-lane src
            __builtin_amdgcn_global_load_lds(AS1(g), AS3(&ts[buf][0]), 4, 0, 0);
        }
    };

    stage(0, 0);
    asm volatile("s_waitcnt vmcnt(0)" ::: "memory");
    __syncthreads();

    int cur = 0;
    for (int p = 0; p < npan; ++p) {
        if (p + 1 < npan) stage(cur ^ 1, p + 1);   // prefetch next panel (other buffer)

#pragma unroll 2
        for (int j = 0; j < PJ; ++j) {
            const float col = ts[cur][j] * (float)(N_ - 1);
            const float ph = row * col;
            float sn, cs;
            sincos_ref(ph, sn, cs);
            const float4* __restrict__ xr =
                reinterpret_cast<const float4*>(&xs[cur][j * C_]);
#pragma unroll
            for (int q = 0; q < C_ / 4; ++q) {
                const float4 v = xr[q];   // ds_read_b128, broadcast (uniform addr)
                accR[4 * q + 0] = fmaf(cs, v.x, accR[4 * q + 0]);
                accI[4 * q + 0] = fmaf(sn, v.x, accI[4 * q + 0]);
                accR[4 * q + 1] = fmaf(cs, v.y, accR[4 * q + 1]);
                accI[4 * q + 1] = fmaf(sn, v.y, accI[4 * q + 1]);
                accR[4 * q + 2] = fmaf(cs, v.z, accR[4 * q + 2]);
                accI[4 * q + 2] = fmaf(sn, v.z, accI[4 * q + 2]);
                accR[4 * q + 3] = fmaf(cs, v.w, accR[4 * q + 3]);
                accI[4 * q + 3] = fmaf(sn, v.w, accI[4 * q + 3]);
            }
        }

        asm volatile("s_waitcnt vmcnt(0)" ::: "memory");  // next panel landed
        __syncthreads();                                   // everyone done reading cur
        cur ^= 1;
    }

    if (DIRECT) {
        float* __restrict__ dst = out + ((size_t)b * S_ + (size_t)s) * C_;
        const bool zero = (s == 0) || (s == S_ - 1);
#pragma unroll
        for (int c = 0; c < C_; ++c) {
            float m = sqrtf(fmaf(accR[c], accR[c], accI[c] * accI[c])) * 0.015625f;
            dst[c] = zero ? 0.f : m;
        }
    } else {
        float* __restrict__ dst =
            part + (((size_t)b * K + (size_t)k) * S_ + (size_t)s) * (2 * C_);
#pragma unroll
        for (int c = 0; c < C_; c += 2) {
            float4 v = make_float4(accR[c], accI[c], accR[c + 1], accI[c + 1]);
            *reinterpret_cast<float4*>(dst + 2 * c) = v;
        }
    }
}

// Reduce K partials, magnitude, zero first/last rows. One thread per (b,s,c).
__global__ __launch_bounds__(256)
void fudft_reduce(const float* __restrict__ part, float* __restrict__ out, int K)
{
    const int idx = blockIdx.x * 256 + threadIdx.x;
    if (idx >= B_ * S_ * C_) return;
    const int c = idx & (C_ - 1);
    const int s = (idx >> 5) & (S_ - 1);
    const int b = idx >> 17;

    float re = 0.f, im = 0.f;
    for (int k = 0; k < K; ++k) {
        const float2 v = *reinterpret_cast<const float2*>(
            part + (((size_t)b * K + (size_t)k) * S_ + (size_t)s) * (2 * C_) + 2 * c);
        re += v.x; im += v.y;
    }
    float m = sqrtf(fmaf(re, re, im * im)) * 0.015625f;  // * 1/sqrt(4096)
    if (s == 0 || s == S_ - 1) m = 0.f;
    out[idx] = m;
}

extern "C" void kernel_launch(void* const* d_in, const int* in_sizes, int n_in,
                              void* d_out, int out_size, void* d_ws, size_t ws_size,
                              hipStream_t stream) {
    const float* x = (const float*)d_in[0];
    const float* t = (const float*)d_in[1];
    const float* f = (const float*)d_in[2];
    float* out = (float*)d_out;

    const size_t bytes_per_k = (size_t)B_ * S_ * 2 * C_ * sizeof(float);  // 4.19 MB
    int K = (int)(ws_size / bytes_per_k);
    if (K >= 16) K = 16; else if (K >= 8) K = 8; else if (K >= 4) K = 4;
    else if (K >= 2) K = 2; else if (K >= 1) K = 1; else K = 0;

    if (K >= 1) {
        const int chunk = N_ / K;   // multiple of PJ for all K choices
        dim3 grid(S_ / 256, K, B_);
        fudft_partial<0><<<grid, 256, 0, stream>>>(x, t, f, (float*)d_ws, out, K, chunk);
        const int total = B_ * S_ * C_;
        fudft_reduce<<<(total + 255) / 256, 256, 0, stream>>>((const float*)d_ws, out, K);
    } else {
        dim3 grid(S_ / 256, 1, B_);
        fudft_partial<1><<<grid, 256, 0, stream>>>(x, t, f, nullptr, out, 1, N_);
    }
}

// Round 3
// 123.093 us; speedup vs baseline: 2.1352x; 1.7162x over previous
//
#include <hip/hip_runtime.h>
#include <math.h>

#define B_ 4
#define N_ 4096
#define C_ 32
#define S_ 4096
#define KSP 2
#define KHALF (N_ / KSP)     // 2048
#define NSTEP (KHALF / 32)   // 64

typedef float f32x4 __attribute__((ext_vector_type(4)));
typedef short s16x8 __attribute__((ext_vector_type(8)));
typedef unsigned int uint_t;
typedef unsigned short ushort_t;

#define AS1(p) ((const __attribute__((address_space(1))) void*)(p))
#define AS3(p) ((__attribute__((address_space(3))) void*)(p))

// ws byte layout
#define PART_BYTES   (B_ * KSP * S_ * 2 * C_ * 4)      // 8388608
#define XTH_OFF      PART_BYTES
#define XTL_OFF      (XTH_OFF + B_ * C_ * N_ * 2)      // +1 MB
#define PSI_OFF      (XTL_OFF + B_ * C_ * N_ * 2)      // +1 MB
#define WS_NEED      (PSI_OFF + B_ * N_ * 4)           // ~10.55 MB

// Extended-precision reduction: r = p/(2pi) mod 1, HW sin/cos take revolutions.
// Same as rounds 1-2 (passed): matches reference sin/cos(fp32 phase) to ~1e-6.
__device__ __forceinline__ void sincos_ref(float p, float& sn, float& cs) {
    const double INV2PI_D = 0.15915494309189535;
    const float HI = (float)INV2PI_D;
    const float LO = (float)(INV2PI_D - (double)HI);
    float hi = p * HI;
    float e  = fmaf(p, HI, -hi);
    e = fmaf(p, LO, e);
    float k = rintf(hi);
    float r = (hi - k) + e;
    sn = __builtin_amdgcn_sinf(r);
    cs = __builtin_amdgcn_cosf(r);
}

// Prep: x[B][N][C] f32 -> xT_hi/xT_lo [B][C][N] bf16 (hi = truncate, lo = residual),
// and psi[B][N] = t*4095 (exact reference fp32 'cols' value).
__global__ __launch_bounds__(256)
void fudft_prep(const float* __restrict__ x, const float* __restrict__ t,
                ushort_t* __restrict__ xTh, ushort_t* __restrict__ xTl,
                float* __restrict__ psi)
{
    const int idx = blockIdx.x * 256 + threadIdx.x;   // B*N*C = 524288
    const int b = idx >> 17, n = (idx >> 5) & (N_ - 1), c = idx & (C_ - 1);
    const float v = x[idx];
    const uint_t bits = __float_as_uint(v);
    const float lo = v - __uint_as_float(bits & 0xffff0000u);
    const int o = (b * C_ + c) * N_ + n;
    xTh[o] = (ushort_t)(bits >> 16);
    xTl[o] = (ushort_t)(__float_as_uint(lo) >> 16);
    if (c == 0) psi[b * N_ + n] = t[b * N_ + n] * (float)(N_ - 1);
}

// Main: per wave one 16-row s-tile. A-frags (cos/sin hi/lo) generated in-register;
// B-frags (xT tile) staged to LDS k-chunk-major (2-way banks) via global_load_lds.
__global__ __launch_bounds__(256, 2)
void fudft_mfma(const float* __restrict__ freqs,
                const ushort_t* __restrict__ xTh,
                const ushort_t* __restrict__ xTl,
                const float* __restrict__ psi,
                float* __restrict__ part)   // [B][KSP][S][C] float2(re,im)
{
    __shared__ ushort_t xs[2][2][4][32][8];  // [buf][plane][kchunk][c][8k] = 8 KB

    const int tid = threadIdx.x;
    const int wid = tid >> 6;
    const int lane = tid & 63;
    const int q = lane >> 4, r = lane & 15;
    const int kk = blockIdx.y, b = blockIdx.z;
    const int sb = blockIdx.x * 64 + wid * 16;

    const float NEG2PI_N = (float)(-2.0 * M_PI / (double)N_);
    const float row = (freqs[sb + r] * (float)(N_ - 1)) * NEG2PI_N;

    // staging source: tid -> (plane, kchunk, c); LDS dst is linear tid*16B
    const int cc = tid & 31, ch = (tid >> 5) & 3, pl = tid >> 7;
    const ushort_t* src = (pl ? xTl : xTh)
                        + ((size_t)(b * C_ + cc)) * N_ + kk * KHALF + ch * 8;
    const float* pp = psi + b * N_ + kk * KHALF + q * 8;

    f32x4 aRe0 = {0,0,0,0}, aRe1 = {0,0,0,0}, aIm0 = {0,0,0,0}, aIm1 = {0,0,0,0};

    __builtin_amdgcn_global_load_lds(AS1(src), AS3((ushort_t*)xs + wid * 512), 16, 0, 0);
    src += 32;
    asm volatile("s_waitcnt vmcnt(0)" ::: "memory");
    __syncthreads();

    int buf = 0;
    for (int step = 0; step < NSTEP; ++step) {
        if (step + 1 < NSTEP) {
            __builtin_amdgcn_global_load_lds(
                AS1(src), AS3((ushort_t*)xs + (buf ^ 1) * 2048 + wid * 512), 16, 0, 0);
            src += 32;
        }
        const float4 p0 = *(const float4*)pp;
        const float4 p1 = *(const float4*)(pp + 4);
        pp += 32;
        const float ph[8] = {p0.x, p0.y, p0.z, p0.w, p1.x, p1.y, p1.z, p1.w};

        uint_t cw[8], sw[8], clw[8], slw[8];
#pragma unroll
        for (int f = 0; f < 8; ++f) {
            const float phase = row * ph[f];     // reference op order: rows*cols
            float sn, cs;
            sincos_ref(phase, sn, cs);
            const uint_t cb = __float_as_uint(cs), sbb = __float_as_uint(sn);
            cw[f] = cb; sw[f] = sbb;
            clw[f] = __float_as_uint(cs - __uint_as_float(cb & 0xffff0000u));
            slw[f] = __float_as_uint(sn - __uint_as_float(sbb & 0xffff0000u));
        }
        union { uint_t w[4]; s16x8 v; } fCH, fCL, fSH, fSL;
#pragma unroll
        for (int j = 0; j < 4; ++j) {
            fCH.w[j] = (cw[2*j]  >> 16) | (cw[2*j+1]  & 0xffff0000u);
            fSH.w[j] = (sw[2*j]  >> 16) | (sw[2*j+1]  & 0xffff0000u);
            fCL.w[j] = (clw[2*j] >> 16) | (clw[2*j+1] & 0xffff0000u);
            fSL.w[j] = (slw[2*j] >> 16) | (slw[2*j+1] & 0xffff0000u);
        }

        // B-frags: int4 index = buf*256 + plane*128 + kchunk(q)*32 + c(nt*16+r)
        const int4* lp = (const int4*)xs + buf * 256 + q * 32 + r;
        union { int4 i; s16x8 v; } bh0, bh1, bl0, bl1;
        bh0.i = lp[0]; bh1.i = lp[16]; bl0.i = lp[128]; bl1.i = lp[144];

        aRe0 = __builtin_amdgcn_mfma_f32_16x16x32_bf16(fCH.v, bh0.v, aRe0, 0, 0, 0);
        aRe0 = __builtin_amdgcn_mfma_f32_16x16x32_bf16(fCL.v, bh0.v, aRe0, 0, 0, 0);
        aRe0 = __builtin_amdgcn_mfma_f32_16x16x32_bf16(fCH.v, bl0.v, aRe0, 0, 0, 0);
        aIm0 = __builtin_amdgcn_mfma_f32_16x16x32_bf16(fSH.v, bh0.v, aIm0, 0, 0, 0);
        aIm0 = __builtin_amdgcn_mfma_f32_16x16x32_bf16(fSL.v, bh0.v, aIm0, 0, 0, 0);
        aIm0 = __builtin_amdgcn_mfma_f32_16x16x32_bf16(fSH.v, bl0.v, aIm0, 0, 0, 0);
        aRe1 = __builtin_amdgcn_mfma_f32_16x16x32_bf16(fCH.v, bh1.v, aRe1, 0, 0, 0);
        aRe1 = __builtin_amdgcn_mfma_f32_16x16x32_bf16(fCL.v, bh1.v, aRe1, 0, 0, 0);
        aRe1 = __builtin_amdgcn_mfma_f32_16x16x32_bf16(fCH.v, bl1.v, aRe1, 0, 0, 0);
        aIm1 = __builtin_amdgcn_mfma_f32_16x16x32_bf16(fSH.v, bh1.v, aIm1, 0, 0, 0);
        aIm1 = __builtin_amdgcn_mfma_f32_16x16x32_bf16(fSL.v, bh1.v, aIm1, 0, 0, 0);
        aIm1 = __builtin_amdgcn_mfma_f32_16x16x32_bf16(fSH.v, bl1.v, aIm1, 0, 0, 0);

        asm volatile("s_waitcnt vmcnt(0)" ::: "memory");
        __syncthreads();
        buf ^= 1;
    }

    // epilogue: D layout col=lane&15, row=(lane>>4)*4+reg (m89-verified)
    float2* pout = (float2*)part + ((size_t)(b * KSP + kk) * S_ + sb) * C_;
#pragma unroll
    for (int reg = 0; reg < 4; ++reg) {
        const int m = q * 4 + reg;
        pout[(size_t)m * C_ + r]      = make_float2(aRe0[reg], aIm0[reg]);
        pout[(size_t)m * C_ + 16 + r] = make_float2(aRe1[reg], aIm1[reg]);
    }
}

__global__ __launch_bounds__(256)
void fudft_reduce2(const float* __restrict__ part, float* __restrict__ out)
{
    const int idx = blockIdx.x * 256 + threadIdx.x;  // B*S*C
    const int c = idx & 31, s = (idx >> 5) & (S_ - 1), b = idx >> 17;
    const float2* p2 = (const float2*)part;
    const float2 v0 = p2[((size_t)(b * KSP + 0) * S_ + s) * C_ + c];
    const float2 v1 = p2[((size_t)(b * KSP + 1) * S_ + s) * C_ + c];
    const float re = v0.x + v1.x, im = v0.y + v1.y;
    const float m = sqrtf(fmaf(re, re, im * im)) * 0.015625f;
    out[idx] = (s == 0 || s == S_ - 1) ? 0.f : m;
}

// Safety fallback (only if ws is too small — not expected): naive direct kernel.
__global__ __launch_bounds__(256)
void fudft_naive(const float* __restrict__ x, const float* __restrict__ t,
                 const float* __restrict__ freqs, float* __restrict__ out)
{
    const int s = blockIdx.x * 256 + threadIdx.x;
    const int b = blockIdx.y;
    const float row = (freqs[s] * (float)(N_ - 1)) * (float)(-2.0 * M_PI / (double)N_);
    float aR[C_], aI[C_];
#pragma unroll
    for (int c = 0; c < C_; ++c) { aR[c] = 0.f; aI[c] = 0.f; }
    for (int n = 0; n < N_; ++n) {
        const float col = t[b * N_ + n] * (float)(N_ - 1);
        float sn, cs; sincos_ref(row * col, sn, cs);
        const float* xr = x + ((size_t)b * N_ + n) * C_;
#pragma unroll
        for (int c = 0; c < C_; ++c) {
            aR[c] = fmaf(cs, xr[c], aR[c]);
            aI[c] = fmaf(sn, xr[c], aI[c]);
        }
    }
    float* dst = out + ((size_t)b * S_ + s) * C_;
    const bool zero = (s == 0) || (s == S_ - 1);
#pragma unroll
    for (int c = 0; c < C_; ++c) {
        const float m = sqrtf(fmaf(aR[c], aR[c], aI[c] * aI[c])) * 0.015625f;
        dst[c] = zero ? 0.f : m;
    }
}

extern "C" void kernel_launch(void* const* d_in, const int* in_sizes, int n_in,
                              void* d_out, int out_size, void* d_ws, size_t ws_size,
                              hipStream_t stream) {
    const float* x = (const float*)d_in[0];
    const float* t = (const float*)d_in[1];
    const float* f = (const float*)d_in[2];
    float* out = (float*)d_out;

    if (ws_size >= (size_t)WS_NEED) {
        char* ws = (char*)d_ws;
        float*    part = (float*)ws;
        ushort_t* xTh  = (ushort_t*)(ws + XTH_OFF);
        ushort_t* xTl  = (ushort_t*)(ws + XTL_OFF);
        float*    psi  = (float*)(ws + PSI_OFF);

        fudft_prep<<<(B_ * N_ * C_) / 256, 256, 0, stream>>>(x, t, xTh, xTl, psi);
        dim3 grid(S_ / 64, KSP, B_);
        fudft_mfma<<<grid, 256, 0, stream>>>(f, xTh, xTl, psi, part);
        fudft_reduce2<<<(B_ * S_ * C_) / 256, 256, 0, stream>>>(part, out);
    } else {
        dim3 grid(S_ / 256, B_);
        fudft_naive<<<grid, 256, 0, stream>>>(x, t, f, out);
    }
}

// Round 4
// 114.606 us; speedup vs baseline: 2.2934x; 1.0740x over previous
//
#include <hip/hip_runtime.h>
#include <math.h>

#define B_ 4
#define N_ 4096
#define C_ 32
#define S_ 4096
#define KSP 8
#define KCH (N_ / KSP)       // 512 k per block
#define NSTEP (KCH / 32)     // 16 steps

typedef float f32x4 __attribute__((ext_vector_type(4)));
typedef short s16x8 __attribute__((ext_vector_type(8)));
typedef unsigned int uint_t;
typedef unsigned short ushort_t;

#define AS1(p) ((const __attribute__((address_space(1))) void*)(p))
#define AS3(p) ((__attribute__((address_space(3))) void*)(p))

// ws byte layout
#define PART_BYTES   (B_ * KSP * S_ * 2 * C_ * 4)      // 33554432
#define XTH_OFF      PART_BYTES
#define XTL_OFF      (XTH_OFF + B_ * C_ * N_ * 2)      // +1 MB
#define PSI_OFF      (XTL_OFF + B_ * C_ * N_ * 2)      // +1 MB
#define WS_NEED      (PSI_OFF + B_ * N_ * 4)           // ~35.7 MB

// Extended-precision reduction: r = p/(2pi) mod 1, HW sin/cos take revolutions.
// Matches reference sin/cos(fp32 phase) to ~1e-6 (validated rounds 1-3).
__device__ __forceinline__ void sincos_ref(float p, float& sn, float& cs) {
    const double INV2PI_D = 0.15915494309189535;
    const float HI = (float)INV2PI_D;
    const float LO = (float)(INV2PI_D - (double)HI);
    float hi = p * HI;
    float e  = fmaf(p, HI, -hi);
    e = fmaf(p, LO, e);
    float k = rintf(hi);
    float r = (hi - k) + e;
    sn = __builtin_amdgcn_sinf(r);
    cs = __builtin_amdgcn_cosf(r);
}

// Prep (LDS-tiled transpose, coalesced both sides):
// x[B][N][C] f32 -> xT_hi/xT_lo [B][C][N] bf16 (hi=truncate, lo=residual),
// psi[B][N] = t*4095. One block per (64-n slab, b).
__global__ __launch_bounds__(256)
void fudft_prep(const float* __restrict__ x, const float* __restrict__ t,
                ushort_t* __restrict__ xTh, ushort_t* __restrict__ xTl,
                float* __restrict__ psi)
{
    __shared__ ushort_t lds[2][64][40];   // [plane][n][c], pad 32->40
    const int tid = threadIdx.x;
    const int n0 = blockIdx.x * 64;
    const int b  = blockIdx.y;

    // ---- load 64x32 f32 slab, coalesced (each thread 8 floats = 32 B) ----
    const float* src = x + ((size_t)b * N_ + n0) * C_;
    const int nl = tid >> 2;           // local n
    const int c0 = (tid & 3) * 8;      // starting c
    const float4 v0 = *(const float4*)(src + (size_t)nl * C_ + c0);
    const float4 v1 = *(const float4*)(src + (size_t)nl * C_ + c0 + 4);
    const float vv[8] = {v0.x, v0.y, v0.z, v0.w, v1.x, v1.y, v1.z, v1.w};
    union { ushort_t u[8]; int4 i; } hp, lp;
#pragma unroll
    for (int j = 0; j < 8; ++j) {
        const uint_t bits = __float_as_uint(vv[j]);
        hp.u[j] = (ushort_t)(bits >> 16);
        const float lo = vv[j] - __uint_as_float(bits & 0xffff0000u);
        lp.u[j] = (ushort_t)(__float_as_uint(lo) >> 16);
    }
    *(int4*)&lds[0][nl][c0] = hp.i;    // 80B row stride: 16B-aligned
    *(int4*)&lds[1][nl][c0] = lp.i;

    if (tid < 64) psi[b * N_ + n0 + tid] = t[b * N_ + n0 + tid] * (float)(N_ - 1);
    __syncthreads();

    // ---- store: 64 rows (plane,c), each 64n*2B = 128 B contiguous ----
    const int row = tid >> 2, qtr = tid & 3;
    const int pl = row >> 5, c = row & 31;
    union { ushort_t u[16]; int4 i[2]; } o;
#pragma unroll
    for (int j = 0; j < 16; ++j) o.u[j] = lds[pl][qtr * 16 + j][c];
    ushort_t* dst = (pl ? xTl : xTh) + ((size_t)(b * C_ + c)) * N_ + n0 + qtr * 16;
    *(int4*)dst = o.i[0];
    *((int4*)dst + 1) = o.i[1];
}

// Main: per wave one 16-row s-tile. A-frags (cos/sin hi/lo) generated in-register;
// B-frags (xT tile) staged to LDS k-chunk-major via global_load_lds, double-buffered.
__global__ __launch_bounds__(256, 8)
void fudft_mfma(const float* __restrict__ freqs,
                const ushort_t* __restrict__ xTh,
                const ushort_t* __restrict__ xTl,
                const float* __restrict__ psi,
                float* __restrict__ part)   // [B][KSP][S][C] float2(re,im)
{
    __shared__ ushort_t xs[2][2][4][32][8];  // [buf][plane][kchunk][c][8k] = 8 KB

    const int tid = threadIdx.x;
    const int wid = tid >> 6;
    const int lane = tid & 63;
    const int q = lane >> 4, r = lane & 15;
    const int kk = blockIdx.y, b = blockIdx.z;
    const int sb = blockIdx.x * 64 + wid * 16;

    const float NEG2PI_N = (float)(-2.0 * M_PI / (double)N_);
    const float row = (freqs[sb + r] * (float)(N_ - 1)) * NEG2PI_N;

    // staging source: tid -> (plane, kchunk, c); LDS dst is linear tid*16B
    const int cc = tid & 31, ch = (tid >> 5) & 3, pl = tid >> 7;
    const ushort_t* src = (pl ? xTl : xTh)
                        + ((size_t)(b * C_ + cc)) * N_ + kk * KCH + ch * 8;
    const float* pp = psi + b * N_ + kk * KCH + q * 8;

    f32x4 aRe0 = {0,0,0,0}, aRe1 = {0,0,0,0}, aIm0 = {0,0,0,0}, aIm1 = {0,0,0,0};

    __builtin_amdgcn_global_load_lds(AS1(src), AS3((ushort_t*)xs + wid * 512), 16, 0, 0);
    src += 32;
    asm volatile("s_waitcnt vmcnt(0)" ::: "memory");
    __syncthreads();

    int buf = 0;
    for (int step = 0; step < NSTEP; ++step) {
        if (step + 1 < NSTEP) {
            __builtin_amdgcn_global_load_lds(
                AS1(src), AS3((ushort_t*)xs + (buf ^ 1) * 2048 + wid * 512), 16, 0, 0);
            src += 32;
        }
        const float4 p0 = *(const float4*)pp;
        const float4 p1 = *(const float4*)(pp + 4);
        pp += 32;
        const float ph[8] = {p0.x, p0.y, p0.z, p0.w, p1.x, p1.y, p1.z, p1.w};

        uint_t cw[8], sw[8], clw[8], slw[8];
#pragma unroll
        for (int f = 0; f < 8; ++f) {
            const float phase = row * ph[f];     // reference op order: rows*cols
            float sn, cs;
            sincos_ref(phase, sn, cs);
            const uint_t cb = __float_as_uint(cs), sbb = __float_as_uint(sn);
            cw[f] = cb; sw[f] = sbb;
            clw[f] = __float_as_uint(cs - __uint_as_float(cb & 0xffff0000u));
            slw[f] = __float_as_uint(sn - __uint_as_float(sbb & 0xffff0000u));
        }
        union { uint_t w[4]; s16x8 v; } fCH, fCL, fSH, fSL;
#pragma unroll
        for (int j = 0; j < 4; ++j) {
            // v_perm_b32: take hi16 of each pair -> one packed word (1 op vs 3)
            fCH.w[j] = __builtin_amdgcn_perm(cw[2*j+1],  cw[2*j],  0x07060302u);
            fSH.w[j] = __builtin_amdgcn_perm(sw[2*j+1],  sw[2*j],  0x07060302u);
            fCL.w[j] = __builtin_amdgcn_perm(clw[2*j+1], clw[2*j], 0x07060302u);
            fSL.w[j] = __builtin_amdgcn_perm(slw[2*j+1], slw[2*j], 0x07060302u);
        }

        // B-frags: int4 index = buf*256 + plane*128 + kchunk(q)*32 + c(nt*16+r)
        const int4* lpx = (const int4*)xs + buf * 256 + q * 32 + r;
        union { int4 i; s16x8 v; } bh0, bh1, bl0, bl1;
        bh0.i = lpx[0]; bh1.i = lpx[16]; bl0.i = lpx[128]; bl1.i = lpx[144];

        aRe0 = __builtin_amdgcn_mfma_f32_16x16x32_bf16(fCH.v, bh0.v, aRe0, 0, 0, 0);
        aRe0 = __builtin_amdgcn_mfma_f32_16x16x32_bf16(fCL.v, bh0.v, aRe0, 0, 0, 0);
        aRe0 = __builtin_amdgcn_mfma_f32_16x16x32_bf16(fCH.v, bl0.v, aRe0, 0, 0, 0);
        aIm0 = __builtin_amdgcn_mfma_f32_16x16x32_bf16(fSH.v, bh0.v, aIm0, 0, 0, 0);
        aIm0 = __builtin_amdgcn_mfma_f32_16x16x32_bf16(fSL.v, bh0.v, aIm0, 0, 0, 0);
        aIm0 = __builtin_amdgcn_mfma_f32_16x16x32_bf16(fSH.v, bl0.v, aIm0, 0, 0, 0);
        aRe1 = __builtin_amdgcn_mfma_f32_16x16x32_bf16(fCH.v, bh1.v, aRe1, 0, 0, 0);
        aRe1 = __builtin_amdgcn_mfma_f32_16x16x32_bf16(fCL.v, bh1.v, aRe1, 0, 0, 0);
        aRe1 = __builtin_amdgcn_mfma_f32_16x16x32_bf16(fCH.v, bl1.v, aRe1, 0, 0, 0);
        aIm1 = __builtin_amdgcn_mfma_f32_16x16x32_bf16(fSH.v, bh1.v, aIm1, 0, 0, 0);
        aIm1 = __builtin_amdgcn_mfma_f32_16x16x32_bf16(fSL.v, bh1.v, aIm1, 0, 0, 0);
        aIm1 = __builtin_amdgcn_mfma_f32_16x16x32_bf16(fSH.v, bl1.v, aIm1, 0, 0, 0);

        asm volatile("s_waitcnt vmcnt(0)" ::: "memory");
        __syncthreads();
        buf ^= 1;
    }

    // epilogue: D layout col=lane&15, row=(lane>>4)*4+reg (m89-verified)
    float2* pout = (float2*)part + ((size_t)(b * KSP + kk) * S_ + sb) * C_;
#pragma unroll
    for (int reg = 0; reg < 4; ++reg) {
        const int m = q * 4 + reg;
        pout[(size_t)m * C_ + r]      = make_float2(aRe0[reg], aIm0[reg]);
        pout[(size_t)m * C_ + 16 + r] = make_float2(aRe1[reg], aIm1[reg]);
    }
}

__global__ __launch_bounds__(256)
void fudft_reduce2(const float* __restrict__ part, float* __restrict__ out)
{
    const int idx = blockIdx.x * 256 + threadIdx.x;  // B*S*C
    const int c = idx & 31, s = (idx >> 5) & (S_ - 1), b = idx >> 17;
    const float2* p2 = (const float2*)part;
    float re = 0.f, im = 0.f;
#pragma unroll
    for (int k = 0; k < KSP; ++k) {
        const float2 v = p2[((size_t)(b * KSP + k) * S_ + s) * C_ + c];
        re += v.x; im += v.y;
    }
    const float m = sqrtf(fmaf(re, re, im * im)) * 0.015625f;
    out[idx] = (s == 0 || s == S_ - 1) ? 0.f : m;
}

// Safety fallback (only if ws is too small — not expected): naive direct kernel.
__global__ __launch_bounds__(256)
void fudft_naive(const float* __restrict__ x, const float* __restrict__ t,
                 const float* __restrict__ freqs, float* __restrict__ out)
{
    const int s = blockIdx.x * 256 + threadIdx.x;
    const int b = blockIdx.y;
    const float row = (freqs[s] * (float)(N_ - 1)) * (float)(-2.0 * M_PI / (double)N_);
    float aR[C_], aI[C_];
#pragma unroll
    for (int c = 0; c < C_; ++c) { aR[c] = 0.f; aI[c] = 0.f; }
    for (int n = 0; n < N_; ++n) {
        const float col = t[b * N_ + n] * (float)(N_ - 1);
        float sn, cs; sincos_ref(row * col, sn, cs);
        const float* xr = x + ((size_t)b * N_ + n) * C_;
#pragma unroll
        for (int c = 0; c < C_; ++c) {
            aR[c] = fmaf(cs, xr[c], aR[c]);
            aI[c] = fmaf(sn, xr[c], aI[c]);
        }
    }
    float* dst = out + ((size_t)b * S_ + s) * C_;
    const bool zero = (s == 0) || (s == S_ - 1);
#pragma unroll
    for (int c = 0; c < C_; ++c) {
        const float m = sqrtf(fmaf(aR[c], aR[c], aI[c] * aI[c])) * 0.015625f;
        dst[c] = zero ? 0.f : m;
    }
}

extern "C" void kernel_launch(void* const* d_in, const int* in_sizes, int n_in,
                              void* d_out, int out_size, void* d_ws, size_t ws_size,
                              hipStream_t stream) {
    const float* x = (const float*)d_in[0];
    const float* t = (const float*)d_in[1];
    const float* f = (const float*)d_in[2];
    float* out = (float*)d_out;

    if (ws_size >= (size_t)WS_NEED) {
        char* ws = (char*)d_ws;
        float*    part = (float*)ws;
        ushort_t* xTh  = (ushort_t*)(ws + XTH_OFF);
        ushort_t* xTl  = (ushort_t*)(ws + XTL_OFF);
        float*    psi  = (float*)(ws + PSI_OFF);

        dim3 gprep(N_ / 64, B_);
        fudft_prep<<<gprep, 256, 0, stream>>>(x, t, xTh, xTl, psi);
        dim3 grid(S_ / 64, KSP, B_);
        fudft_mfma<<<grid, 256, 0, stream>>>(f, xTh, xTl, psi, part);
        fudft_reduce2<<<(B_ * S_ * C_) / 256, 256, 0, stream>>>(part, out);
    } else {
        dim3 grid(S_ / 256, B_);
        fudft_naive<<<grid, 256, 0, stream>>>(x, t, f, out);
    }
}

// Round 5
// 110.754 us; speedup vs baseline: 2.3731x; 1.0348x over previous
//
#include <hip/hip_runtime.h>
#include <math.h>

#define B_ 4
#define N_ 4096
#define C_ 32
#define S_ 4096
#define KSP 4
#define KCH (N_ / KSP)       // 1024 k per block
#define NSTEP (KCH / 32)     // 32 steps

typedef float f32x4 __attribute__((ext_vector_type(4)));
typedef short s16x8 __attribute__((ext_vector_type(8)));
typedef unsigned int uint_t;
typedef unsigned short ushort_t;

#define AS1(p) ((const __attribute__((address_space(1))) void*)(p))
#define AS3(p) ((__attribute__((address_space(3))) void*)(p))

// ws byte layout
#define PART_BYTES   (B_ * KSP * S_ * 2 * C_ * 4)      // 16777216
#define XTH_OFF      PART_BYTES
#define XTL_OFF      (XTH_OFF + B_ * C_ * N_ * 2)      // +1 MB
#define PSI_OFF      (XTL_OFF + B_ * C_ * N_ * 2)      // +1 MB
#define WS_NEED      (PSI_OFF + B_ * N_ * 4)           // ~18.9 MB

// Extended-precision reduction: r = p/(2pi) mod 1, HW sin/cos take revolutions.
// Matches reference sin/cos(fp32 phase) to ~1e-6 (validated rounds 1-4).
__device__ __forceinline__ void sincos_ref(float p, float& sn, float& cs) {
    const double INV2PI_D = 0.15915494309189535;
    const float HI = (float)INV2PI_D;
    const float LO = (float)(INV2PI_D - (double)HI);
    float hi = p * HI;
    float e  = fmaf(p, HI, -hi);
    e = fmaf(p, LO, e);
    float k = rintf(hi);
    float r = (hi - k) + e;
    sn = __builtin_amdgcn_sinf(r);
    cs = __builtin_amdgcn_cosf(r);
}

// Prep (LDS-tiled transpose, coalesced both sides):
// x[B][N][C] f32 -> xT_hi/xT_lo [B][C][N] bf16 (hi=truncate, lo=residual),
// psi[B][N] = t*4095. One block per (64-n slab, b).
__global__ __launch_bounds__(256)
void fudft_prep(const float* __restrict__ x, const float* __restrict__ t,
                ushort_t* __restrict__ xTh, ushort_t* __restrict__ xTl,
                float* __restrict__ psi)
{
    __shared__ ushort_t lds[2][64][40];   // [plane][n][c], pad 32->40
    const int tid = threadIdx.x;
    const int n0 = blockIdx.x * 64;
    const int b  = blockIdx.y;

    const float* src = x + ((size_t)b * N_ + n0) * C_;
    const int nl = tid >> 2;           // local n
    const int c0 = (tid & 3) * 8;      // starting c
    const float4 v0 = *(const float4*)(src + (size_t)nl * C_ + c0);
    const float4 v1 = *(const float4*)(src + (size_t)nl * C_ + c0 + 4);
    const float vv[8] = {v0.x, v0.y, v0.z, v0.w, v1.x, v1.y, v1.z, v1.w};
    union { ushort_t u[8]; int4 i; } hp, lp;
#pragma unroll
    for (int j = 0; j < 8; ++j) {
        const uint_t bits = __float_as_uint(vv[j]);
        hp.u[j] = (ushort_t)(bits >> 16);
        const float lo = vv[j] - __uint_as_float(bits & 0xffff0000u);
        lp.u[j] = (ushort_t)(__float_as_uint(lo) >> 16);
    }
    *(int4*)&lds[0][nl][c0] = hp.i;
    *(int4*)&lds[1][nl][c0] = lp.i;

    if (tid < 64) psi[b * N_ + n0 + tid] = t[b * N_ + n0 + tid] * (float)(N_ - 1);
    __syncthreads();

    const int row = tid >> 2, qtr = tid & 3;
    const int pl = row >> 5, c = row & 31;
    union { ushort_t u[16]; int4 i[2]; } o;
#pragma unroll
    for (int j = 0; j < 16; ++j) o.u[j] = lds[pl][qtr * 16 + j][c];
    ushort_t* dst = (pl ? xTl : xTh) + ((size_t)(b * C_ + c)) * N_ + n0 + qtr * 16;
    *(int4*)dst = o.i[0];
    *((int4*)dst + 1) = o.i[1];
}

// Main: per wave one 16-row s-tile (4 waves = 64 rows/block), K split across
// blockIdx.y. A-frags (cos/sin hi/lo) generated in-register from psi (register
// double-buffered, loads issued FIRST so the compiler's wait leaves the stage
// in flight); B-frags from a block-shared LDS tile staged via global_load_lds.
__global__ __launch_bounds__(256, 4)
void fudft_mfma(const float* __restrict__ freqs,
                const ushort_t* __restrict__ xTh,
                const ushort_t* __restrict__ xTl,
                const float* __restrict__ psi,
                float* __restrict__ part)   // [B][KSP][S][C] float2(re,im)
{
    __shared__ ushort_t xs[2][2][4][32][8];  // [buf][plane][kchunk][c][8k] = 8 KB

    const int tid = threadIdx.x;
    const int wid = tid >> 6;
    const int lane = tid & 63;
    const int q = lane >> 4, r = lane & 15;
    const int kk = blockIdx.y, b = blockIdx.z;
    const int sb = blockIdx.x * 64 + wid * 16;

    const float NEG2PI_N = (float)(-2.0 * M_PI / (double)N_);
    const float row = (freqs[sb + r] * (float)(N_ - 1)) * NEG2PI_N;

    // staging source: tid -> (plane, kchunk, c); LDS dst is wave-uniform base
    const int cc = tid & 31, ch = (tid >> 5) & 3, pl = tid >> 7;
    const ushort_t* src = (pl ? xTl : xTh)
                        + ((size_t)(b * C_ + cc)) * N_ + kk * KCH + ch * 8;
    const float* pp = psi + b * N_ + kk * KCH + q * 8;

    f32x4 aRe0 = {0,0,0,0}, aRe1 = {0,0,0,0}, aIm0 = {0,0,0,0}, aIm1 = {0,0,0,0};

    // prologue: psi[0] into regs, stage step 0
    float4 pc0 = *(const float4*)pp;
    float4 pc1 = *(const float4*)(pp + 4);
    __builtin_amdgcn_global_load_lds(AS1(src), AS3((ushort_t*)xs + wid * 512), 16, 0, 0);
    src += 32;
    asm volatile("s_waitcnt vmcnt(0)" ::: "memory");
    __syncthreads();

    int buf = 0;
    for (int step = 0; step < NSTEP; ++step) {
        // 1) psi[step+1] loads FIRST (oldest outstanding -> cheap wait next iter)
        float4 pn0, pn1;
        if (step + 1 < NSTEP) {
            const float* pnx = pp + (step + 1) * 32;
            pn0 = *(const float4*)pnx;
            pn1 = *(const float4*)(pnx + 4);
        }
        // 2) stage next tile (stays in flight across the whole body)
        if (step + 1 < NSTEP) {
            __builtin_amdgcn_global_load_lds(
                AS1(src), AS3((ushort_t*)xs + (buf ^ 1) * 2048 + wid * 512), 16, 0, 0);
            src += 32;
        }

        // 3) A-frag generation from current psi regs (no VMEM wait needed)
        const float ph[8] = {pc0.x, pc0.y, pc0.z, pc0.w, pc1.x, pc1.y, pc1.z, pc1.w};
        uint_t cw[8], sw[8], clw[8], slw[8];
#pragma unroll
        for (int f = 0; f < 8; ++f) {
            const float phase = row * ph[f];     // reference op order: rows*cols
            float sn, cs;
            sincos_ref(phase, sn, cs);
            const uint_t cb = __float_as_uint(cs), sbb = __float_as_uint(sn);
            cw[f] = cb; sw[f] = sbb;
            clw[f] = __float_as_uint(cs - __uint_as_float(cb & 0xffff0000u));
            slw[f] = __float_as_uint(sn - __uint_as_float(sbb & 0xffff0000u));
        }
        union { uint_t w[4]; s16x8 v; } fCH, fCL, fSH, fSL;
#pragma unroll
        for (int j = 0; j < 4; ++j) {
            fCH.w[j] = __builtin_amdgcn_perm(cw[2*j+1],  cw[2*j],  0x07060302u);
            fSH.w[j] = __builtin_amdgcn_perm(sw[2*j+1],  sw[2*j],  0x07060302u);
            fCL.w[j] = __builtin_amdgcn_perm(clw[2*j+1], clw[2*j], 0x07060302u);
            fSL.w[j] = __builtin_amdgcn_perm(slw[2*j+1], slw[2*j], 0x07060302u);
        }

        // 4) B-frags from current LDS buffer
        const int4* lpx = (const int4*)xs + buf * 256 + q * 32 + r;
        union { int4 i; s16x8 v; } bh0, bh1, bl0, bl1;
        bh0.i = lpx[0]; bh1.i = lpx[16]; bl0.i = lpx[128]; bl1.i = lpx[144];

        aRe0 = __builtin_amdgcn_mfma_f32_16x16x32_bf16(fCH.v, bh0.v, aRe0, 0, 0, 0);
        aRe0 = __builtin_amdgcn_mfma_f32_16x16x32_bf16(fCL.v, bh0.v, aRe0, 0, 0, 0);
        aRe0 = __builtin_amdgcn_mfma_f32_16x16x32_bf16(fCH.v, bl0.v, aRe0, 0, 0, 0);
        aIm0 = __builtin_amdgcn_mfma_f32_16x16x32_bf16(fSH.v, bh0.v, aIm0, 0, 0, 0);
        aIm0 = __builtin_amdgcn_mfma_f32_16x16x32_bf16(fSL.v, bh0.v, aIm0, 0, 0, 0);
        aIm0 = __builtin_amdgcn_mfma_f32_16x16x32_bf16(fSH.v, bl0.v, aIm0, 0, 0, 0);
        aRe1 = __builtin_amdgcn_mfma_f32_16x16x32_bf16(fCH.v, bh1.v, aRe1, 0, 0, 0);
        aRe1 = __builtin_amdgcn_mfma_f32_16x16x32_bf16(fCL.v, bh1.v, aRe1, 0, 0, 0);
        aRe1 = __builtin_amdgcn_mfma_f32_16x16x32_bf16(fCH.v, bl1.v, aRe1, 0, 0, 0);
        aIm1 = __builtin_amdgcn_mfma_f32_16x16x32_bf16(fSH.v, bh1.v, aIm1, 0, 0, 0);
        aIm1 = __builtin_amdgcn_mfma_f32_16x16x32_bf16(fSL.v, bh1.v, aIm1, 0, 0, 0);
        aIm1 = __builtin_amdgcn_mfma_f32_16x16x32_bf16(fSH.v, bl1.v, aIm1, 0, 0, 0);

        // 5) single drain: stage (and psi_next) have had the whole body to land
        asm volatile("s_waitcnt vmcnt(0)" ::: "memory");
        __syncthreads();
        pc0 = pn0; pc1 = pn1;
        buf ^= 1;
    }

    // epilogue: D layout col=lane&15, row=(lane>>4)*4+reg (m89-verified)
    float2* pout = (float2*)part + ((size_t)(b * KSP + kk) * S_ + sb) * C_;
#pragma unroll
    for (int reg = 0; reg < 4; ++reg) {
        const int m = q * 4 + reg;
        pout[(size_t)m * C_ + r]      = make_float2(aRe0[reg], aIm0[reg]);
        pout[(size_t)m * C_ + 16 + r] = make_float2(aRe1[reg], aIm1[reg]);
    }
}

// Reduce KSP partials, magnitude, zero first/last rows. One thread per (b,s,2c).
__global__ __launch_bounds__(256)
void fudft_reduce2(const float* __restrict__ part, float* __restrict__ out)
{
    const int idx = blockIdx.x * 256 + threadIdx.x;  // B*S*C/2 threads
    const int c2 = (idx & 15) * 2;
    const int s = (idx >> 4) & (S_ - 1);
    const int b = idx >> 16;
    float re0 = 0.f, im0 = 0.f, re1 = 0.f, im1 = 0.f;
#pragma unroll
    for (int k = 0; k < KSP; ++k) {
        const float4 v = *(const float4*)(part
            + (((size_t)(b * KSP + k) * S_ + s) * C_ + c2) * 2);
        re0 += v.x; im0 += v.y; re1 += v.z; im1 += v.w;
    }
    float m0 = sqrtf(fmaf(re0, re0, im0 * im0)) * 0.015625f;
    float m1 = sqrtf(fmaf(re1, re1, im1 * im1)) * 0.015625f;
    if (s == 0 || s == S_ - 1) { m0 = 0.f; m1 = 0.f; }
    *(float2*)(out + ((size_t)b * S_ + s) * C_ + c2) = make_float2(m0, m1);
}

// Safety fallback (only if ws is too small — not expected): naive direct kernel.
__global__ __launch_bounds__(256)
void fudft_naive(const float* __restrict__ x, const float* __restrict__ t,
                 const float* __restrict__ freqs, float* __restrict__ out)
{
    const int s = blockIdx.x * 256 + threadIdx.x;
    const int b = blockIdx.y;
    const float row = (freqs[s] * (float)(N_ - 1)) * (float)(-2.0 * M_PI / (double)N_);
    float aR[C_], aI[C_];
#pragma unroll
    for (int c = 0; c < C_; ++c) { aR[c] = 0.f; aI[c] = 0.f; }
    for (int n = 0; n < N_; ++n) {
        const float col = t[b * N_ + n] * (float)(N_ - 1);
        float sn, cs; sincos_ref(row * col, sn, cs);
        const float* xr = x + ((size_t)b * N_ + n) * C_;
#pragma unroll
        for (int c = 0; c < C_; ++c) {
            aR[c] = fmaf(cs, xr[c], aR[c]);
            aI[c] = fmaf(sn, xr[c], aI[c]);
        }
    }
    float* dst = out + ((size_t)b * S_ + s) * C_;
    const bool zero = (s == 0) || (s == S_ - 1);
#pragma unroll
    for (int c = 0; c < C_; ++c) {
        const float m = sqrtf(fmaf(aR[c], aR[c], aI[c] * aI[c])) * 0.015625f;
        dst[c] = zero ? 0.f : m;
    }
}

extern "C" void kernel_launch(void* const* d_in, const int* in_sizes, int n_in,
                              void* d_out, int out_size, void* d_ws, size_t ws_size,
                              hipStream_t stream) {
    const float* x = (const float*)d_in[0];
    const float* t = (const float*)d_in[1];
    const float* f = (const float*)d_in[2];
    float* out = (float*)d_out;

    if (ws_size >= (size_t)WS_NEED) {
        char* ws = (char*)d_ws;
        float*    part = (float*)ws;
        ushort_t* xTh  = (ushort_t*)(ws + XTH_OFF);
        ushort_t* xTl  = (ushort_t*)(ws + XTL_OFF);
        float*    psi  = (float*)(ws + PSI_OFF);

        dim3 gprep(N_ / 64, B_);
        fudft_prep<<<gprep, 256, 0, stream>>>(x, t, xTh, xTl, psi);
        dim3 grid(S_ / 64, KSP, B_);
        fudft_mfma<<<grid, 256, 0, stream>>>(f, xTh, xTl, psi, part);
        fudft_reduce2<<<(B_ * S_ * C_ / 2) / 256, 256, 0, stream>>>(part, out);
    } else {
        dim3 grid(S_ / 256, B_);
        fudft_naive<<<grid, 256, 0, stream>>>(x, t, f, out);
    }
}

// Round 7
// 109.465 us; speedup vs baseline: 2.4011x; 1.0118x over previous
//
#include <hip/hip_runtime.h>
#include <hip/hip_fp16.h>
#include <math.h>

#define B_ 4
#define N_ 4096
#define C_ 32
#define S_ 4096
#define NSTEP 32              // 1024 k per k-wave, 32 k per step

typedef float f32x4 __attribute__((ext_vector_type(4)));
typedef _Float16 f16x8 __attribute__((ext_vector_type(8)));
typedef __fp16 fp16x2 __attribute__((ext_vector_type(2)));
typedef unsigned int uint_t;
typedef unsigned short ushort_t;

#define AS1(p) ((const __attribute__((address_space(1))) void*)(p))
#define AS3(p) ((__attribute__((address_space(3))) void*)(p))

// ws byte layout (no partials anymore)
#define XTH_OFF 0
#define XTL_OFF (B_ * C_ * N_ * 2)            // 1 MB
#define PSI_OFF (XTL_OFF + B_ * C_ * N_ * 2)  // 2 MB
#define WS_NEED (PSI_OFF + B_ * N_ * 4)       // ~2.1 MB

// Extended-precision reduction: r = p/(2pi) mod 1, HW sin/cos take revolutions.
// Matches reference sin/cos(fp32 phase) to ~1e-6 (validated rounds 1-5).
__device__ __forceinline__ void sincos_ref(float p, float& sn, float& cs) {
    const double INV2PI_D = 0.15915494309189535;
    const float HI = (float)INV2PI_D;
    const float LO = (float)(INV2PI_D - (double)HI);
    float hi = p * HI;
    float e  = fmaf(p, HI, -hi);
    e = fmaf(p, LO, e);
    float k = rintf(hi);
    float r = (hi - k) + e;
    sn = __builtin_amdgcn_sinf(r);
    cs = __builtin_amdgcn_cosf(r);
}

__device__ __forceinline__ uint_t pkrtz(float a, float b) {
    union { fp16x2 h; uint_t w; } u;
    u.h = __builtin_amdgcn_cvt_pkrtz(a, b);
    return u.w;
}

// Prep (LDS-tiled transpose, coalesced both sides):
// x[B][N][C] f32 -> xT_hi/xT_lo [B][C][N] f16 (hi = RTN, lo = residual RTN),
// psi[B][N] = t*4095. One block per (64-n slab, b).
__global__ __launch_bounds__(256)
void fudft_prep(const float* __restrict__ x, const float* __restrict__ t,
                ushort_t* __restrict__ xTh, ushort_t* __restrict__ xTl,
                float* __restrict__ psi)
{
    __shared__ ushort_t lds[2][64][40];   // [plane][n][c], pad 32->40
    const int tid = threadIdx.x;
    const int n0 = blockIdx.x * 64;
    const int b  = blockIdx.y;

    const float* src = x + ((size_t)b * N_ + n0) * C_;
    const int nl = tid >> 2;           // local n
    const int c0 = (tid & 3) * 8;      // starting c
    const float4 v0 = *(const float4*)(src + (size_t)nl * C_ + c0);
    const float4 v1 = *(const float4*)(src + (size_t)nl * C_ + c0 + 4);
    const float vv[8] = {v0.x, v0.y, v0.z, v0.w, v1.x, v1.y, v1.z, v1.w};
    union { ushort_t u[8]; int4 i; } hp, lp;
#pragma unroll
    for (int j = 0; j < 8; ++j) {
        const __half h = __float2half_rn(vv[j]);
        hp.u[j] = __half_as_ushort(h);
        const float rem = vv[j] - __half2float(h);
        lp.u[j] = __half_as_ushort(__float2half_rn(rem));
    }
    *(int4*)&lds[0][nl][c0] = hp.i;
    *(int4*)&lds[1][nl][c0] = lp.i;

    if (tid < 64) psi[b * N_ + n0 + tid] = t[b * N_ + n0 + tid] * (float)(N_ - 1);
    __syncthreads();

    const int row = tid >> 2, qtr = tid & 3;
    const int pl = row >> 5, c = row & 31;
    union { ushort_t u[16]; int4 i[2]; } o;
#pragma unroll
    for (int j = 0; j < 16; ++j) o.u[j] = lds[pl][qtr * 16 + j][c];
    ushort_t* dst = (pl ? xTl : xTh) + ((size_t)(b * C_ + c)) * N_ + n0 + qtr * 16;
    *(int4*)dst = o.i[0];
    *((int4*)dst + 1) = o.i[1];
}

// Main: 512 threads = 8 waves = 2 s-subtiles (ws) x 4 k-chunks (wk).
// Block covers 32 s-rows x full K=4096; cross-wave LDS reduction in epilogue
// writes FINAL output (no partials kernel). A-frags = f16 trig (single plane,
// cvt_pkrtz); B-frags = f16 x hi+lo planes from LDS staged via global_load_lds.
__global__ __launch_bounds__(512, 4)
void fudft_mfma(const float* __restrict__ freqs,
                const ushort_t* __restrict__ xTh,
                const ushort_t* __restrict__ xTl,
                const float* __restrict__ psi,
                float* __restrict__ out)     // [B][S][C]
{
    // 0..32767: staging [buf2][ch4][pl2][oct4][c32][k8] f16
    // 32768..57343: reduction buffer 6144 floats
    __shared__ __align__(16) char smem[32768 + 24576];
    ushort_t* st = (ushort_t*)smem;
    float* red = (float*)(smem + 32768);

    const int tid = threadIdx.x;
    const int w   = tid >> 6;
    const int lane = tid & 63;
    const int q = lane >> 4, r = lane & 15;
    const int ws = w & 1, wk = w >> 1;
    const int b = blockIdx.y;
    const int sb = blockIdx.x * 32 + ws * 16;

    const float NEG2PI_N = (float)(-2.0 * M_PI / (double)N_);
    const float row = (freqs[sb + r] * (float)(N_ - 1)) * NEG2PI_N;

    // staging assignment: unit u = w*2+i covers 512 f16 = [2 octs][32 c][8 k]
    const int u0 = w * 2, u1 = w * 2 + 1;
    const int ch0 = u0 >> 2, pl0 = (u0 >> 1) & 1, ob0 = (u0 & 1) * 2 + (lane >> 5);
    const int ch1 = u1 >> 2, pl1 = (u1 >> 1) & 1, ob1 = (u1 & 1) * 2 + (lane >> 5);
    const int cl = lane & 31;
    const ushort_t* src0 = (pl0 ? xTl : xTh) + ((size_t)(b * C_ + cl)) * N_ + ch0 * 1024 + ob0 * 8;
    const ushort_t* src1 = (pl1 ? xTl : xTh) + ((size_t)(b * C_ + cl)) * N_ + ch1 * 1024 + ob1 * 8;

    const float* pp = psi + b * N_ + wk * 1024 + q * 8;

    f32x4 aRe0 = {0,0,0,0}, aRe1 = {0,0,0,0}, aIm0 = {0,0,0,0}, aIm1 = {0,0,0,0};

    auto stage = [&](int buf) {
        __builtin_amdgcn_global_load_lds(AS1(src0), AS3(st + buf * 8192 + u0 * 512), 16, 0, 0);
        __builtin_amdgcn_global_load_lds(AS1(src1), AS3(st + buf * 8192 + u1 * 512), 16, 0, 0);
        src0 += 32; src1 += 32;
    };

    // prologue
    float4 pc0 = *(const float4*)pp;
    float4 pc1 = *(const float4*)(pp + 4);
    stage(0);
    asm volatile("s_waitcnt vmcnt(0)" ::: "memory");
    __syncthreads();

    int buf = 0;
    for (int step = 0; step < NSTEP; ++step) {
        // psi[step+1] first, then next stage — all stay in flight across the body
        float4 pn0 = make_float4(0.f,0.f,0.f,0.f), pn1 = pn0;
        if (step + 1 < NSTEP) {
            const float* pnx = pp + (step + 1) * 32;
            pn0 = *(const float4*)pnx;
            pn1 = *(const float4*)(pnx + 4);
            stage(buf ^ 1);
        }

        // A-frags: f16 trig, single plane
        const float ph[8] = {pc0.x, pc0.y, pc0.z, pc0.w, pc1.x, pc1.y, pc1.z, pc1.w};
        float csv[8], snv[8];
#pragma unroll
        for (int f = 0; f < 8; ++f) {
            const float phase = row * ph[f];    // reference op order: rows*cols
            sincos_ref(phase, snv[f], csv[f]);
        }
        union { uint_t wd[4]; f16x8 v; } fC, fS;
#pragma unroll
        for (int j = 0; j < 4; ++j) {
            fC.wd[j] = pkrtz(csv[2*j], csv[2*j+1]);
            fS.wd[j] = pkrtz(snv[2*j], snv[2*j+1]);
        }

        // B-frags: [buf][wk][pl][oct=q][c=r /r+16][8k]
        const int4* lpx = (const int4*)smem + buf * 1024 + wk * 256 + q * 32 + r;
        union { int4 i; f16x8 v; } bh0, bh1, bl0, bl1;
        bh0.i = lpx[0]; bh1.i = lpx[16]; bl0.i = lpx[128]; bl1.i = lpx[144];

        aRe0 = __builtin_amdgcn_mfma_f32_16x16x32_f16(fC.v, bh0.v, aRe0, 0, 0, 0);
        aRe0 = __builtin_amdgcn_mfma_f32_16x16x32_f16(fC.v, bl0.v, aRe0, 0, 0, 0);
        aIm0 = __builtin_amdgcn_mfma_f32_16x16x32_f16(fS.v, bh0.v, aIm0, 0, 0, 0);
        aIm0 = __builtin_amdgcn_mfma_f32_16x16x32_f16(fS.v, bl0.v, aIm0, 0, 0, 0);
        aRe1 = __builtin_amdgcn_mfma_f32_16x16x32_f16(fC.v, bh1.v, aRe1, 0, 0, 0);
        aRe1 = __builtin_amdgcn_mfma_f32_16x16x32_f16(fC.v, bl1.v, aRe1, 0, 0, 0);
        aIm1 = __builtin_amdgcn_mfma_f32_16x16x32_f16(fS.v, bh1.v, aIm1, 0, 0, 0);
        aIm1 = __builtin_amdgcn_mfma_f32_16x16x32_f16(fS.v, bl1.v, aIm1, 0, 0, 0);

        asm volatile("s_waitcnt vmcnt(0)" ::: "memory");
        __syncthreads();
        pc0 = pn0; pc1 = pn1;
        buf ^= 1;
    }

    // ---- cross-wave K reduction over wk=0..3 (per ws) ----
    if (wk > 0) {
        const int slot = (wk - 1) * 2 + ws;
        float* rb = red + slot * 1024 + lane * 4;
        *(f32x4*)(rb)       = aRe0;
        *(f32x4*)(rb + 256) = aIm0;
        *(f32x4*)(rb + 512) = aRe1;
        *(f32x4*)(rb + 768) = aIm1;
    }
    __syncthreads();
    if (wk == 0) {
#pragma unroll
        for (int sl = 0; sl < 3; ++sl) {
            const float* rb = red + (sl * 2 + ws) * 1024 + lane * 4;
            aRe0 += *(const f32x4*)(rb);
            aIm0 += *(const f32x4*)(rb + 256);
            aRe1 += *(const f32x4*)(rb + 512);
            aIm1 += *(const f32x4*)(rb + 768);
        }
        // epilogue: D layout col=lane&15, row=(lane>>4)*4+reg (m89-verified)
        float* pout = out + ((size_t)b * S_ + sb) * C_;
#pragma unroll
        for (int reg = 0; reg < 4; ++reg) {
            const int m = q * 4 + reg;
            const int sg = sb + m;
            const bool zero = (sg == 0) || (sg == S_ - 1);
            float m0 = sqrtf(fmaf(aRe0[reg], aRe0[reg], aIm0[reg] * aIm0[reg])) * 0.015625f;
            float m1 = sqrtf(fmaf(aRe1[reg], aRe1[reg], aIm1[reg] * aIm1[reg])) * 0.015625f;
            pout[(size_t)m * C_ + r]      = zero ? 0.f : m0;
            pout[(size_t)m * C_ + 16 + r] = zero ? 0.f : m1;
        }
    }
}

// Safety fallback (only if ws too small — not expected): naive direct kernel.
__global__ __launch_bounds__(256)
void fudft_naive(const float* __restrict__ x, const float* __restrict__ t,
                 const float* __restrict__ freqs, float* __restrict__ out)
{
    const int s = blockIdx.x * 256 + threadIdx.x;
    const int b = blockIdx.y;
    const float row = (freqs[s] * (float)(N_ - 1)) * (float)(-2.0 * M_PI / (double)N_);
    float aR[C_], aI[C_];
#pragma unroll
    for (int c = 0; c < C_; ++c) { aR[c] = 0.f; aI[c] = 0.f; }
    for (int n = 0; n < N_; ++n) {
        const float col = t[b * N_ + n] * (float)(N_ - 1);
        float sn, cs; sincos_ref(row * col, sn, cs);
        const float* xr = x + ((size_t)b * N_ + n) * C_;
#pragma unroll
        for (int c = 0; c < C_; ++c) {
            aR[c] = fmaf(cs, xr[c], aR[c]);
            aI[c] = fmaf(sn, xr[c], aI[c]);
        }
    }
    float* dst = out + ((size_t)b * S_ + s) * C_;
    const bool zero = (s == 0) || (s == S_ - 1);
#pragma unroll
    for (int c = 0; c < C_; ++c) {
        const float m = sqrtf(fmaf(aR[c], aR[c], aI[c] * aI[c])) * 0.015625f;
        dst[c] = zero ? 0.f : m;
    }
}

extern "C" void kernel_launch(void* const* d_in, const int* in_sizes, int n_in,
                              void* d_out, int out_size, void* d_ws, size_t ws_size,
                              hipStream_t stream) {
    const float* x = (const float*)d_in[0];
    const float* t = (const float*)d_in[1];
    const float* f = (const float*)d_in[2];
    float* out = (float*)d_out;

    if (ws_size >= (size_t)WS_NEED) {
        char* ws = (char*)d_ws;
        ushort_t* xTh = (ushort_t*)(ws + XTH_OFF);
        ushort_t* xTl = (ushort_t*)(ws + XTL_OFF);
        float*    psi = (float*)(ws + PSI_OFF);

        dim3 gprep(N_ / 64, B_);
        fudft_prep<<<gprep, 256, 0, stream>>>(x, t, xTh, xTl, psi);
        dim3 grid(S_ / 32, B_);
        fudft_mfma<<<grid, 512, 0, stream>>>(f, xTh, xTl, psi, out);
    } else {
        dim3 grid(S_ / 256, B_);
        fudft_naive<<<grid, 256, 0, stream>>>(x, t, f, out);
    }
}

// Round 8
// 81.910 us; speedup vs baseline: 3.2088x; 1.3364x over previous
//
#include <hip/hip_runtime.h>
#include <hip/hip_fp16.h>
#include <math.h>

#define B_ 4
#define N_ 4096
#define C_ 32
#define S_ 4096
#define KW 512       // k per wave (8 waves k-split in block)
#define NSTEP 16     // 32 k per step

typedef float f32x4 __attribute__((ext_vector_type(4)));
typedef _Float16 f16x8 __attribute__((ext_vector_type(8)));
typedef __fp16 fp16x2 __attribute__((ext_vector_type(2)));
typedef unsigned int uint_t;
typedef unsigned short ushort_t;

// ws layout
#define XTH_OFF 0
#define PSI_OFF (B_ * C_ * N_ * 2)           // 1 MB
#define WS_NEED (PSI_OFF + B_ * N_ * 4)      // ~1.1 MB

__device__ __forceinline__ uint_t pkrtz(float a, float b) {
    union { fp16x2 h; uint_t w; } u;
    u.h = __builtin_amdgcn_cvt_pkrtz(a, b);
    return u.w;
}

// Accurate reduction (fallback path only)
__device__ __forceinline__ void sincos_ref(float p, float& sn, float& cs) {
    const double INV2PI_D = 0.15915494309189535;
    const float HI = (float)INV2PI_D;
    const float LO = (float)(INV2PI_D - (double)HI);
    float hi = p * HI;
    float e  = fmaf(p, HI, -hi);
    e = fmaf(p, LO, e);
    float k = rintf(hi);
    float r = (hi - k) + e;
    sn = __builtin_amdgcn_sinf(r);
    cs = __builtin_amdgcn_cosf(r);
}

// Prep: x[B][N][C] f32 -> xTh [B][C][N] f16 (RTN), psi[B][N] = t*4095.
// LDS-tiled transpose, coalesced both sides. One block per (64-n slab, b).
__global__ __launch_bounds__(256)
void fudft_prep(const float* __restrict__ x, const float* __restrict__ t,
                ushort_t* __restrict__ xTh, float* __restrict__ psi)
{
    __shared__ ushort_t lds[64][40];   // pad 32->40
    const int tid = threadIdx.x;
    const int n0 = blockIdx.x * 64;
    const int b  = blockIdx.y;

    const float* src = x + ((size_t)b * N_ + n0) * C_;
    const int nl = tid >> 2, c0 = (tid & 3) * 8;
    const float4 v0 = *(const float4*)(src + (size_t)nl * C_ + c0);
    const float4 v1 = *(const float4*)(src + (size_t)nl * C_ + c0 + 4);
    const float vv[8] = {v0.x, v0.y, v0.z, v0.w, v1.x, v1.y, v1.z, v1.w};
    union { ushort_t u[8]; int4 i; } hp;
#pragma unroll
    for (int j = 0; j < 8; ++j) hp.u[j] = __half_as_ushort(__float2half_rn(vv[j]));
    *(int4*)&lds[nl][c0] = hp.i;

    if (tid < 64) psi[b * N_ + n0 + tid] = t[b * N_ + n0 + tid] * (float)(N_ - 1);
    __syncthreads();

    const int c = tid >> 3, oct = tid & 7;   // 32 c-rows x 8 threads
    union { ushort_t u[8]; int4 i; } o;
#pragma unroll
    for (int j = 0; j < 8; ++j) o.u[j] = lds[oct * 8 + j][c];
    *(int4*)(xTh + ((size_t)(b * C_ + c)) * N_ + n0 + oct * 8) = o.i;
}

#define MFMA16(A, Bv, Acc) __builtin_amdgcn_mfma_f32_16x16x32_f16(A, Bv, Acc, 0, 0, 0)

// Main: barrier-free inner loop. Wave = 32 s-rows x 512 k; B-fragments are
// lane-private -> loaded straight to VGPRs (no LDS staging, no syncs); the
// compiler pipelines loads freely. 8 waves k-split; one LDS reduction at end.
__global__ __launch_bounds__(512, 4)
void fudft_mfma(const float* __restrict__ freqs,
                const ushort_t* __restrict__ xTh,
                const float* __restrict__ psi,
                float* __restrict__ out)     // [B][S][C]
{
    __shared__ float red[14336];   // 7 waves x 8 accs x 64 lanes x f32x4 = 56 KB

    const int tid = threadIdx.x;
    const int wk = tid >> 6;           // k-chunk 0..7
    const int lane = tid & 63;
    const int q = lane >> 4, r = lane & 15;
    const int b = blockIdx.y;
    const int sb = blockIdx.x * 32;

    // fast-trig row factor: rev = rowrev * psi; 2^-12 scale is EXACT.
    const float rr0 = -(freqs[sb + r]      * (float)(N_ - 1)) * 0.000244140625f;
    const float rr1 = -(freqs[sb + 16 + r] * (float)(N_ - 1)) * 0.000244140625f;

    const float* pp = psi + b * N_ + wk * KW + q * 8;
    const ushort_t* xb0 = xTh + ((size_t)(b * C_ + r)) * N_ + wk * KW + q * 8;
    const ushort_t* xb1 = xb0 + 16 * N_;

    f32x4 aRe0a = {0,0,0,0}, aIm0a = {0,0,0,0}, aRe0b = {0,0,0,0}, aIm0b = {0,0,0,0};
    f32x4 aRe1a = {0,0,0,0}, aIm1a = {0,0,0,0}, aRe1b = {0,0,0,0}, aIm1b = {0,0,0,0};

#pragma unroll 4
    for (int s = 0; s < NSTEP; ++s) {
        const float4 p0 = *(const float4*)(pp + s * 32);
        const float4 p1 = *(const float4*)(pp + s * 32 + 4);
        union { int4 i; f16x8 v; } b0, b1;
        b0.i = *(const int4*)(xb0 + s * 32);
        b1.i = *(const int4*)(xb1 + s * 32);

        const float ph[8] = {p0.x, p0.y, p0.z, p0.w, p1.x, p1.y, p1.z, p1.w};
        float c0v[8], s0v[8], c1v[8], s1v[8];
#pragma unroll
        for (int j = 0; j < 8; ++j) {
            float rv0 = rr0 * ph[j]; rv0 -= floorf(rv0);   // v_fract
            s0v[j] = __builtin_amdgcn_sinf(rv0);           // sin(2*pi*rev)
            c0v[j] = __builtin_amdgcn_cosf(rv0);
            float rv1 = rr1 * ph[j]; rv1 -= floorf(rv1);
            s1v[j] = __builtin_amdgcn_sinf(rv1);
            c1v[j] = __builtin_amdgcn_cosf(rv1);
        }
        union { uint_t w[4]; f16x8 v; } fC0, fS0, fC1, fS1;
#pragma unroll
        for (int j = 0; j < 4; ++j) {
            fC0.w[j] = pkrtz(c0v[2*j], c0v[2*j+1]);
            fS0.w[j] = pkrtz(s0v[2*j], s0v[2*j+1]);
            fC1.w[j] = pkrtz(c1v[2*j], c1v[2*j+1]);
            fS1.w[j] = pkrtz(s1v[2*j], s1v[2*j+1]);
        }
        aRe0a = MFMA16(fC0.v, b0.v, aRe0a);  aRe0b = MFMA16(fC0.v, b1.v, aRe0b);
        aIm0a = MFMA16(fS0.v, b0.v, aIm0a);  aIm0b = MFMA16(fS0.v, b1.v, aIm0b);
        aRe1a = MFMA16(fC1.v, b0.v, aRe1a);  aRe1b = MFMA16(fC1.v, b1.v, aRe1b);
        aIm1a = MFMA16(fS1.v, b0.v, aIm1a);  aIm1b = MFMA16(fS1.v, b1.v, aIm1b);
    }

    // ---- single cross-wave reduction over wk = 0..7 ----
    if (wk > 0) {
        float* rb = red + (size_t)(wk - 1) * 8 * 256 + lane * 4;
        *(f32x4*)(rb + 0*256) = aRe0a;  *(f32x4*)(rb + 1*256) = aIm0a;
        *(f32x4*)(rb + 2*256) = aRe0b;  *(f32x4*)(rb + 3*256) = aIm0b;
        *(f32x4*)(rb + 4*256) = aRe1a;  *(f32x4*)(rb + 5*256) = aIm1a;
        *(f32x4*)(rb + 6*256) = aRe1b;  *(f32x4*)(rb + 7*256) = aIm1b;
    }
    __syncthreads();
    if (wk == 0) {
#pragma unroll
        for (int sl = 0; sl < 7; ++sl) {
            const float* rb = red + (size_t)sl * 8 * 256 + lane * 4;
            aRe0a += *(const f32x4*)(rb + 0*256);  aIm0a += *(const f32x4*)(rb + 1*256);
            aRe0b += *(const f32x4*)(rb + 2*256);  aIm0b += *(const f32x4*)(rb + 3*256);
            aRe1a += *(const f32x4*)(rb + 4*256);  aIm1a += *(const f32x4*)(rb + 5*256);
            aRe1b += *(const f32x4*)(rb + 6*256);  aIm1b += *(const f32x4*)(rb + 7*256);
        }
        // D layout col=lane&15, row=(lane>>4)*4+reg (m89-verified)
        float* po = out + ((size_t)b * S_ + sb) * C_;
#pragma unroll
        for (int reg = 0; reg < 4; ++reg) {
            const int m0 = q * 4 + reg, m1 = 16 + q * 4 + reg;
            const bool z0 = (sb + m0 == 0) || (sb + m0 == S_ - 1);
            const bool z1 = (sb + m1 == 0) || (sb + m1 == S_ - 1);
            float v;
            v = sqrtf(fmaf(aRe0a[reg], aRe0a[reg], aIm0a[reg]*aIm0a[reg])) * 0.015625f;
            po[(size_t)m0 * C_ + r]      = z0 ? 0.f : v;
            v = sqrtf(fmaf(aRe0b[reg], aRe0b[reg], aIm0b[reg]*aIm0b[reg])) * 0.015625f;
            po[(size_t)m0 * C_ + 16 + r] = z0 ? 0.f : v;
            v = sqrtf(fmaf(aRe1a[reg], aRe1a[reg], aIm1a[reg]*aIm1a[reg])) * 0.015625f;
            po[(size_t)m1 * C_ + r]      = z1 ? 0.f : v;
            v = sqrtf(fmaf(aRe1b[reg], aRe1b[reg], aIm1b[reg]*aIm1b[reg])) * 0.015625f;
            po[(size_t)m1 * C_ + 16 + r] = z1 ? 0.f : v;
        }
    }
}

// Safety fallback (only if ws too small — not expected): naive direct kernel.
__global__ __launch_bounds__(256)
void fudft_naive(const float* __restrict__ x, const float* __restrict__ t,
                 const float* __restrict__ freqs, float* __restrict__ out)
{
    const int s = blockIdx.x * 256 + threadIdx.x;
    const int b = blockIdx.y;
    const float row = (freqs[s] * (float)(N_ - 1)) * (float)(-2.0 * M_PI / (double)N_);
    float aR[C_], aI[C_];
#pragma unroll
    for (int c = 0; c < C_; ++c) { aR[c] = 0.f; aI[c] = 0.f; }
    for (int n = 0; n < N_; ++n) {
        const float col = t[b * N_ + n] * (float)(N_ - 1);
        float sn, cs; sincos_ref(row * col, sn, cs);
        const float* xr = x + ((size_t)b * N_ + n) * C_;
#pragma unroll
        for (int c = 0; c < C_; ++c) {
            aR[c] = fmaf(cs, xr[c], aR[c]);
            aI[c] = fmaf(sn, xr[c], aI[c]);
        }
    }
    float* dst = out + ((size_t)b * S_ + s) * C_;
    const bool zero = (s == 0) || (s == S_ - 1);
#pragma unroll
    for (int c = 0; c < C_; ++c) {
        const float m = sqrtf(fmaf(aR[c], aR[c], aI[c] * aI[c])) * 0.015625f;
        dst[c] = zero ? 0.f : m;
    }
}

extern "C" void kernel_launch(void* const* d_in, const int* in_sizes, int n_in,
                              void* d_out, int out_size, void* d_ws, size_t ws_size,
                              hipStream_t stream) {
    const float* x = (const float*)d_in[0];
    const float* t = (const float*)d_in[1];
    const float* f = (const float*)d_in[2];
    float* out = (float*)d_out;

    if (ws_size >= (size_t)WS_NEED) {
        char* ws = (char*)d_ws;
        ushort_t* xTh = (ushort_t*)(ws + XTH_OFF);
        float*    psi = (float*)(ws + PSI_OFF);

        dim3 gprep(N_ / 64, B_);
        fudft_prep<<<gprep, 256, 0, stream>>>(x, t, xTh, psi);
        dim3 grid(S_ / 32, B_);
        fudft_mfma<<<grid, 512, 0, stream>>>(f, xTh, psi, out);
    } else {
        dim3 grid(S_ / 256, B_);
        fudft_naive<<<grid, 256, 0, stream>>>(x, t, f, out);
    }
}